// Round 9
// baseline (256.840 us; speedup 1.0000x reference)
//
#include <hip/hip_runtime.h>
#include <hip/hip_bf16.h>

typedef __bf16 bf16;
typedef __bf16 bf16x8 __attribute__((ext_vector_type(8)));
typedef float floatx4 __attribute__((ext_vector_type(4)));

#define B_ROWS 4096
#define IN_DIM 512
#define DIM 1024
#define NG 10

__device__ __forceinline__ float geluf(float x) {
    return 0.5f * x * (1.0f + erff(x * 0.70710678118654752f));
}

// async global->LDS, 16B per lane; LDS dest = wave-uniform base + lane*16
__device__ __forceinline__ void async16(void* lds, const void* g) {
    __builtin_amdgcn_global_load_lds(
        (const __attribute__((address_space(1))) unsigned int*)g,
        (__attribute__((address_space(3))) unsigned int*)lds, 16, 0, 0);
}
// s_waitcnt vmcnt(N) only (lgkm=15, exp=7 -> no wait): imm = 0x0F70|N
#define WAIT_VM(N) __builtin_amdgcn_s_waitcnt(0x0F70 | (N))
#define BARRIER() __builtin_amdgcn_s_barrier()

// ---------------------------------------------------------------------------
// prep body: ng = bf16( mu[g] + (|sigma[g]|+eps) * z ). Pure elementwise.
// pb in [0,1024): 256 threads x 8 floats each.  [green: R1/R7]
// ---------------------------------------------------------------------------
__device__ __forceinline__ void prep_body(int pb, const int* __restrict__ genre,
                                          const float* __restrict__ z,
                                          const float* __restrict__ mu_t,
                                          const float* __restrict__ sg_t,
                                          bf16* __restrict__ ng) {
    const int t = pb * 256 + threadIdx.x;
    const int row = t >> 6;
    const int c0 = (t & 63) * 8;
    const int g = genre[row];
    const float* zp = z + (size_t)row * IN_DIM + c0;
    const float* mp = mu_t + (size_t)g * IN_DIM + c0;
    const float* sp = sg_t + (size_t)g * IN_DIM + c0;
    floatx4 z0 = *(const floatx4*)zp, z1 = *(const floatx4*)(zp + 4);
    floatx4 m0 = *(const floatx4*)mp, m1 = *(const floatx4*)(mp + 4);
    floatx4 s0 = *(const floatx4*)sp, s1 = *(const floatx4*)(sp + 4);
    bf16x8 o;
#pragma unroll
    for (int i = 0; i < 4; i++) {
        o[i] = (bf16)(m0[i] + (fabsf(s0[i]) + 1e-8f) * z0[i]);
        o[i + 4] = (bf16)(m1[i] + (fabsf(s1[i]) + 1e-8f) * z1[i]);
    }
    *(bf16x8*)(ng + (size_t)row * IN_DIM + c0) = o;
}

// ---------------------------------------------------------------------------
// bucket body (256 thr): per-wave histograms, serial prefix on thread 0,
// per-wave-base scatter. Order within a bucket is arbitrary (gather/scatter
// both use row_ids consistently).  [green: R1/R7]
// ---------------------------------------------------------------------------
__device__ __forceinline__ void bucket_body(const int* __restrict__ genre,
                                            int* __restrict__ counts,
                                            int* __restrict__ offsets,
                                            int* __restrict__ row_ids,
                                            int* sh) {
    int* whist = sh;           // [4][NG]
    int* wbase = sh + 4 * NG;  // [4][NG]
    const int tid = threadIdx.x;
    const int wave = tid >> 6;
    if (tid < 4 * NG) whist[tid] = 0;
    __syncthreads();
    int g[16];
#pragma unroll
    for (int i = 0; i < 16; i++) {
        g[i] = genre[tid + i * 256];
        atomicAdd(&whist[wave * NG + g[i]], 1);
    }
    __syncthreads();
    if (tid == 0) {
        int acc = 0;
        for (int e = 0; e < NG; e++) {
            int tot = 0;
            for (int w = 0; w < 4; w++) {
                wbase[w * NG + e] = acc + tot;
                tot += whist[w * NG + e];
            }
            counts[e] = tot;
            offsets[e] = acc;
            acc += tot;
        }
        offsets[NG] = acc;
    }
    __syncthreads();
#pragma unroll
    for (int i = 0; i < 16; i++) {
        int pos = atomicAdd(&wbase[wave * NG + g[i]], 1);
        row_ids[pos] = tid + i * 256;
    }
}

// ---------------------------------------------------------------------------
// transpose body: 2 row-adjacent 64x64 tiles of [R][1024] fp32 ->
// [1024][R] bf16 (32 KB LDS, XOR swizzle).  [green: R1/R7]
// ---------------------------------------------------------------------------
__device__ __forceinline__ void transpose_body(const float* __restrict__ src,
                                               bf16* __restrict__ dst, int R,
                                               int b, float* T /*[2][4096]*/) {
    const int r0 = (b >> 4) * 128;
    const int c0 = (b & 15) * 64;
    const int tid = threadIdx.x;
#pragma unroll
    for (int t = 0; t < 2; t++)
#pragma unroll
        for (int i = 0; i < 4; i++) {
            const int s = i * 256 + tid;
            const int r = s >> 4;
            const int cv = s & 15;
            floatx4 v = *(const floatx4*)(src + (size_t)(r0 + t * 64 + r) * 1024 +
                                          c0 + cv * 4);
            *(floatx4*)(T + t * 4096 + r * 64 + ((cv ^ (r >> 3)) * 4)) = v;
        }
    __syncthreads();
#pragma unroll
    for (int t = 0; t < 2; t++)
#pragma unroll
        for (int i = 0; i < 2; i++) {
            const int s = i * 256 + tid;
            const int oc = s >> 3;
            const int og = s & 7;
            const int cg = oc >> 2, o = oc & 3;
            bf16x8 v;
#pragma unroll
            for (int u = 0; u < 8; u++) {
                const int r = og * 8 + u;
                v[u] = (bf16)T[t * 4096 + r * 64 + ((cg ^ (r >> 3)) * 4) + o];
            }
            *(bf16x8*)(dst + (size_t)(c0 + oc) * R + r0 + t * 64 + og * 8) = v;
        }
}

// ---------------------------------------------------------------------------
// GEMM body: C = act(A @ BT^T + bias). A [M][K] bf16, BT [N][K] bf16.
// 128M x 128N tile (m97 geometry: 4 waves, 4x4 frags of 16x16), BK=64,
// DOUBLE-BUFFERED async staging with counted vmcnt: per iter issue 8
// global_load_lds into nxt, s_waitcnt vmcnt(8) (waits only cur's 8), raw
// s_barrier, compute cur (32 MFMA/wave), raw s_barrier. LDS 2x(16+16)KB =
// 64 KB -> 2 blocks/CU. Source-side XOR octet swizzle: slot s ->
// (row=s>>3, oct=(s&7)^(row&7)); fragment ds_read_b128 2-way max (free).
// EXPERT: gz = genre; rows are bucket positions [0,count) at offsets[g].
// [green: R1/R7.  NOTE: BN=64 variant fused with transpose at
//  __launch_bounds__(256,3) fails deterministically (R4/R6) — banned.]
// ---------------------------------------------------------------------------
template <bool EXPERT, bool GATHER_A, bool SCATTER_C, bool GELU, typename CT>
__device__ __forceinline__ void gemm_body(
    int bx, int by, int gz, const bf16* __restrict__ A,
    const bf16* __restrict__ BT, const float* __restrict__ bias,
    CT* __restrict__ Cmat, int N, int K, const int* __restrict__ row_ids,
    const int* __restrict__ offsets, const int* __restrict__ counts,
    bf16* As /*[2][8192]*/, bf16* Bs /*[2][8192]*/) {
    int off = 0, cnt = 1 << 30;
    if (EXPERT) {
        cnt = counts[gz];
        if (by * 128 >= cnt) return;
        off = offsets[gz];
        BT += (size_t)gz * N * K;
        bias += (size_t)gz * N;
    }
    const int m_start = by * 128;
    const int n0 = bx * 128;

    constexpr int BK = 64;  // 8 octets per row
    const int tid = threadIdx.x;
    const int lane = tid & 63;
    const int wave = tid >> 6;
    const int wrow = (wave >> 1) * 64;
    const int wcol = (wave & 1) * 64;
    const int quad = lane >> 4;
    const int l16 = lane & 15;

    // A staging: 1024 slots (128 rows x 8 octets), 4 issues of 256
    const bf16* a_src[4];
#pragma unroll
    for (int i = 0; i < 4; i++) {
        const int s = i * 256 + tid;
        const int row = s >> 3;
        const int col = ((s & 7) ^ (row & 7)) * 8;
        int p = m_start + row;
        size_t arow;
        if (EXPERT) {
            int pp = off + min(p, cnt - 1);
            arow = GATHER_A ? (size_t)row_ids[pp] : (size_t)pp;
        } else {
            arow = (size_t)p;
        }
        a_src[i] = A + arow * (size_t)K + col;
    }
    // B staging: 1024 slots (128 rows x 8 octets), 4 issues
    const bf16* b_src[4];
#pragma unroll
    for (int i = 0; i < 4; i++) {
        const int s = i * 256 + tid;
        const int row = s >> 3;
        const int col = ((s & 7) ^ (row & 7)) * 8;
        b_src[i] = BT + (size_t)(n0 + row) * K + col;
    }
    const int ldsbase = wave * 512;  // wave-uniform (bf16 units); HW adds lane*16B

    floatx4 acc[4][4];
#pragma unroll
    for (int i = 0; i < 4; i++)
#pragma unroll
        for (int j = 0; j < 4; j++)
#pragma unroll
            for (int r = 0; r < 4; r++) acc[i][j][r] = 0.0f;

    const int nK = K / BK;
    // prologue: k=0 into buf0
#pragma unroll
    for (int i = 0; i < 4; i++) async16(&As[i * 2048 + ldsbase], a_src[i]);
#pragma unroll
    for (int i = 0; i < 4; i++) async16(&Bs[i * 2048 + ldsbase], b_src[i]);

    for (int kt = 0; kt < nK; kt++) {
        const int cur = kt & 1, nxt = cur ^ 1;
        const int kn = (kt + 1 < nK) ? (kt + 1) * BK : 0;  // clamp: harmless
#pragma unroll
        for (int i = 0; i < 4; i++)
            async16(&As[nxt * 8192 + i * 2048 + ldsbase], a_src[i] + kn);
#pragma unroll
        for (int i = 0; i < 4; i++)
            async16(&Bs[nxt * 8192 + i * 2048 + ldsbase], b_src[i] + kn);
        WAIT_VM(8);  // cur's 8 loads done; nxt's 8 still in flight
        BARRIER();
#pragma unroll
        for (int ks = 0; ks < 2; ks++) {
            bf16x8 af[4], bfr[4];
            const int cb = ks * 4 + quad;
#pragma unroll
            for (int i = 0; i < 4; i++) {
                const int r = wrow + i * 16 + l16;
                af[i] = *(const bf16x8*)(&As[cur * 8192 + (r * 8 + (cb ^ (r & 7))) * 8]);
            }
#pragma unroll
            for (int j = 0; j < 4; j++) {
                const int n = wcol + j * 16 + l16;
                bfr[j] = *(const bf16x8*)(&Bs[cur * 8192 + (n * 8 + (cb ^ (n & 7))) * 8]);
            }
#pragma unroll
            for (int i = 0; i < 4; i++)
#pragma unroll
                for (int j = 0; j < 4; j++)
                    acc[i][j] = __builtin_amdgcn_mfma_f32_16x16x32_bf16(
                        af[i], bfr[j], acc[i][j], 0, 0, 0);
        }
        BARRIER();  // protect cur before next iter overwrites it
    }

    // epilogue: C/D layout col = lane&15, row = quad*4 + reg  [m89-verified]
#pragma unroll
    for (int j = 0; j < 4; j++) {
        const int n = n0 + wcol + j * 16 + l16;
        const float bv = bias[n];
#pragma unroll
        for (int i = 0; i < 4; i++) {
            const int rbase = wrow + i * 16 + quad * 4;
#pragma unroll
            for (int r = 0; r < 4; r++) {
                const int p = m_start + rbase + r;
                if (EXPERT && p >= cnt) continue;
                float v = acc[i][j][r] + bv;
                if (GELU) v = geluf(v);
                size_t drow;
                if (EXPERT) {
                    const int pp = off + p;
                    drow = SCATTER_C ? (size_t)row_ids[pp] : (size_t)pp;
                } else {
                    drow = (size_t)p;
                }
                Cmat[drow * (size_t)N + n] = (CT)v;
            }
        }
    }
}

// ---------------------------------------------------------------------------
// D1: bucket (block 0, starts first) + ALL weight transposes + prep.
// Round-8 change: We1/We2 transposes (2560 blocks, 120 MB — the BW pole)
// moved here from D2/D3 so they overlap bucket latency + prep, and D2/D3
// become pure GEMM. Block map: [0] bucket | [1,1281) We1 | [1281,2561) We2
// | [2561,3585) prep | [3585,3649) Ws1 | [3649,3777) Ws2.
// ---------------------------------------------------------------------------
__global__ void setup_kernel(const int* __restrict__ genre,
                             const float* __restrict__ z,
                             const float* __restrict__ mu_t,
                             const float* __restrict__ sg_t,
                             bf16* __restrict__ ng,
                             const float* __restrict__ Ws1,
                             const float* __restrict__ Ws2,
                             const float* __restrict__ We1,
                             const float* __restrict__ We2,
                             bf16* __restrict__ WT1, bf16* __restrict__ WT2,
                             bf16* __restrict__ WE1T, bf16* __restrict__ WE2T,
                             int* __restrict__ counts,
                             int* __restrict__ offsets,
                             int* __restrict__ row_ids) {
    __shared__ float T[2 * 4096];  // 32 KB; bucket aliases first 80 ints
    const int b = blockIdx.x;
    if (b == 0) {
        bucket_body(genre, counts, offsets, row_ids, (int*)T);
    } else if (b < 1281) {
        const int u = b - 1;
        const int e = u >> 7;
        transpose_body(We1 + (size_t)e * DIM * DIM, WE1T + (size_t)e * DIM * DIM,
                       1024, u & 127, T);
    } else if (b < 2561) {
        const int u = b - 1281;
        const int e = u >> 7;
        transpose_body(We2 + (size_t)e * DIM * DIM, WE2T + (size_t)e * DIM * DIM,
                       1024, u & 127, T);
    } else if (b < 3585) {
        prep_body(b - 2561, genre, z, mu_t, sg_t, ng);
    } else if (b < 3649) {
        transpose_body(Ws1, WT1, 512, b - 3585, T);
    } else {
        transpose_body(Ws2, WT2, 1024, b - 3649, T);
    }
}

// ---------------------------------------------------------------------------
// D2/D3: PURE shared-MLP GEMM, 256 blocks (8 bx x 32 by), BN=128 at
// (256,2) — byte-identical gemm_body path to the green R1/R7 fused call,
// minus the co-resident transpose blocks.
// ---------------------------------------------------------------------------
__global__ __launch_bounds__(256, 2) void mlp_gemm_kernel(
    const bf16* __restrict__ Ain, const bf16* __restrict__ WT,
    const float* __restrict__ bias, bf16* __restrict__ Sout, int K) {
    __shared__ bf16 smem[32768];  // 64 KB: As[2][8192] | Bs[2][8192]
    gemm_body<false, false, false, true, bf16>(
        blockIdx.x, blockIdx.y, 0, Ain, WT, bias, Sout, DIM, K, nullptr,
        nullptr, nullptr, smem, smem + 16384);
}

// ---------------------------------------------------------------------------
// D4/D5: expert GEMMs. grid (8, 32, 10); blocks past the bucket count
// return immediately.  [green: R1/R7 verbatim]
// ---------------------------------------------------------------------------
template <bool GATHER_A, bool SCATTER_C, bool GELU, typename CT>
__global__ __launch_bounds__(256, 2) void expert_gemm_kernel(
    const bf16* __restrict__ A, const bf16* __restrict__ BT,
    const float* __restrict__ bias, CT* __restrict__ Cmat,
    const int* __restrict__ row_ids, const int* __restrict__ offsets,
    const int* __restrict__ counts) {
    __shared__ bf16 smem[32768];
    gemm_body<true, GATHER_A, SCATTER_C, GELU, CT>(
        blockIdx.x, blockIdx.y, blockIdx.z, A, BT, bias, Cmat, DIM, DIM,
        row_ids, offsets, counts, smem, smem + 16384);
}

extern "C" void kernel_launch(void* const* d_in, const int* in_sizes, int n_in,
                              void* d_out, int out_size, void* d_ws,
                              size_t ws_size, hipStream_t stream) {
    const int* genre = (const int*)d_in[1];
    const float* z = (const float*)d_in[2];
    const float* mu_t = (const float*)d_in[3];
    const float* sg_t = (const float*)d_in[4];
    const float* Ws1 = (const float*)d_in[5];
    const float* bs1 = (const float*)d_in[6];
    const float* Ws2 = (const float*)d_in[7];
    const float* bs2 = (const float*)d_in[8];
    const float* We1 = (const float*)d_in[9];
    const float* be1 = (const float*)d_in[10];
    const float* We2 = (const float*)d_in[11];
    const float* be2 = (const float*)d_in[12];
    float* out = (float*)d_out;
    char* w = (char*)d_ws;

    // Workspace (~63.1 MB): ints first, weights last.  [green: R1/R7]
    int* counts = (int*)w;
    int* offsets = (int*)(w + 256);
    int* row_ids = (int*)(w + 1024);
    char* wb = w + (64 << 10);
    bf16* ng = (bf16*)wb;                          // [4096][512]  4 MB
    bf16* hp = (bf16*)wb;                          // [4096][1024] 8 MB (aliases ng+s1 head; both dead by D4)
    bf16* s1 = (bf16*)(wb + ((size_t)4 << 20));    // 8 MB
    bf16* s2 = (bf16*)(wb + ((size_t)12 << 20));   // 8 MB
    bf16* WT1 = (bf16*)(wb + ((size_t)20 << 20));  // [1024][512]  1 MB
    bf16* WT2 = WT1 + (size_t)IN_DIM * DIM;        // [1024][1024] 2 MB
    bf16* WE1T = WT2 + (size_t)DIM * DIM;          // 10x[1024][1024] 20 MB
    bf16* WE2T = WE1T + (size_t)NG * DIM * DIM;    // 20 MB

    // D1: bucket + ALL transposes + prep (3777 blocks)
    setup_kernel<<<3777, 256, 0, stream>>>(genre, z, mu_t, sg_t, ng, Ws1, Ws2,
                                           We1, We2, WT1, WT2, WE1T, WE2T,
                                           counts, offsets, row_ids);
    // D2: shared MLP layer 1 (K=512), pure GEMM
    mlp_gemm_kernel<<<dim3(8, 32), 256, 0, stream>>>(ng, WT1, bs1, s1, IN_DIM);
    // D3: shared MLP layer 2 (K=1024), pure GEMM
    mlp_gemm_kernel<<<dim3(8, 32), 256, 0, stream>>>(s1, WT2, bs2, s2, DIM);
    // D4: expert layer 1: gather rows by bucket, gelu, write permuted h
    expert_gemm_kernel<true, false, true, bf16>
        <<<dim3(8, 32, 10), 256, 0, stream>>>(s2, WE1T, be1, hp, row_ids,
                                              offsets, counts);
    // D5: expert layer 2: contiguous permuted h, scatter rows to fp32 out
    expert_gemm_kernel<false, true, false, float>
        <<<dim3(8, 32, 10), 256, 0, stream>>>(hp, WE2T, be2, out, row_ids,
                                              offsets, counts);
}

// Round 10
// 247.359 us; speedup vs baseline: 1.0383x; 1.0383x over previous
//
#include <hip/hip_runtime.h>
#include <hip/hip_bf16.h>

typedef __bf16 bf16;
typedef __bf16 bf16x8 __attribute__((ext_vector_type(8)));
typedef float floatx4 __attribute__((ext_vector_type(4)));

#define B_ROWS 4096
#define IN_DIM 512
#define DIM 1024
#define NG 10

__device__ __forceinline__ float geluf(float x) {
    return 0.5f * x * (1.0f + erff(x * 0.70710678118654752f));
}

// async global->LDS, 16B per lane; LDS dest = wave-uniform base + lane*16
__device__ __forceinline__ void async16(void* lds, const void* g) {
    __builtin_amdgcn_global_load_lds(
        (const __attribute__((address_space(1))) unsigned int*)g,
        (__attribute__((address_space(3))) unsigned int*)lds, 16, 0, 0);
}
// s_waitcnt vmcnt(N) only (lgkm=15, exp=7 -> no wait): imm = 0x0F70|N
#define WAIT_VM(N) __builtin_amdgcn_s_waitcnt(0x0F70 | (N))
#define BARRIER() __builtin_amdgcn_s_barrier()

// ---------------------------------------------------------------------------
// prep body: ng = bf16( mu[g] + (|sigma[g]|+eps) * z ). Pure elementwise.
// pb in [0,1024): 256 threads x 8 floats each.
// ---------------------------------------------------------------------------
__device__ __forceinline__ void prep_body(int pb, const int* __restrict__ genre,
                                          const float* __restrict__ z,
                                          const float* __restrict__ mu_t,
                                          const float* __restrict__ sg_t,
                                          bf16* __restrict__ ng) {
    const int t = pb * 256 + threadIdx.x;
    const int row = t >> 6;
    const int c0 = (t & 63) * 8;
    const int g = genre[row];
    const float* zp = z + (size_t)row * IN_DIM + c0;
    const float* mp = mu_t + (size_t)g * IN_DIM + c0;
    const float* sp = sg_t + (size_t)g * IN_DIM + c0;
    floatx4 z0 = *(const floatx4*)zp, z1 = *(const floatx4*)(zp + 4);
    floatx4 m0 = *(const floatx4*)mp, m1 = *(const floatx4*)(mp + 4);
    floatx4 s0 = *(const floatx4*)sp, s1 = *(const floatx4*)(sp + 4);
    bf16x8 o;
#pragma unroll
    for (int i = 0; i < 4; i++) {
        o[i] = (bf16)(m0[i] + (fabsf(s0[i]) + 1e-8f) * z0[i]);
        o[i + 4] = (bf16)(m1[i] + (fabsf(s1[i]) + 1e-8f) * z1[i]);
    }
    *(bf16x8*)(ng + (size_t)row * IN_DIM + c0) = o;
}

// ---------------------------------------------------------------------------
// bucket body (256 thr): per-wave histograms (4x less same-address atomic
// contention than single hist), serial prefix on thread 0, per-wave-base
// scatter. Order within a bucket is arbitrary (gather/scatter both use
// row_ids consistently).
// ---------------------------------------------------------------------------
__device__ __forceinline__ void bucket_body(const int* __restrict__ genre,
                                            int* __restrict__ counts,
                                            int* __restrict__ offsets,
                                            int* __restrict__ row_ids,
                                            int* sh) {
    int* whist = sh;           // [4][NG]
    int* wbase = sh + 4 * NG;  // [4][NG]
    const int tid = threadIdx.x;
    const int wave = tid >> 6;
    if (tid < 4 * NG) whist[tid] = 0;
    __syncthreads();
    int g[16];
#pragma unroll
    for (int i = 0; i < 16; i++) {
        g[i] = genre[tid + i * 256];
        atomicAdd(&whist[wave * NG + g[i]], 1);
    }
    __syncthreads();
    if (tid == 0) {
        int acc = 0;
        for (int e = 0; e < NG; e++) {
            int tot = 0;
            for (int w = 0; w < 4; w++) {
                wbase[w * NG + e] = acc + tot;
                tot += whist[w * NG + e];
            }
            counts[e] = tot;
            offsets[e] = acc;
            acc += tot;
        }
        offsets[NG] = acc;
    }
    __syncthreads();
#pragma unroll
    for (int i = 0; i < 16; i++) {
        int pos = atomicAdd(&wbase[wave * NG + g[i]], 1);
        row_ids[pos] = tid + i * 256;
    }
}

// ---------------------------------------------------------------------------
// transpose body: 2 row-adjacent 64x64 tiles of [R][1024] fp32 ->
// [1024][R] bf16 (32 KB LDS, XOR swizzle).
// ---------------------------------------------------------------------------
__device__ __forceinline__ void transpose_body(const float* __restrict__ src,
                                               bf16* __restrict__ dst, int R,
                                               int b, float* T /*[2][4096]*/) {
    const int r0 = (b >> 4) * 128;
    const int c0 = (b & 15) * 64;
    const int tid = threadIdx.x;
#pragma unroll
    for (int t = 0; t < 2; t++)
#pragma unroll
        for (int i = 0; i < 4; i++) {
            const int s = i * 256 + tid;
            const int r = s >> 4;
            const int cv = s & 15;
            floatx4 v = *(const floatx4*)(src + (size_t)(r0 + t * 64 + r) * 1024 +
                                          c0 + cv * 4);
            *(floatx4*)(T + t * 4096 + r * 64 + ((cv ^ (r >> 3)) * 4)) = v;
        }
    __syncthreads();
#pragma unroll
    for (int t = 0; t < 2; t++)
#pragma unroll
        for (int i = 0; i < 2; i++) {
            const int s = i * 256 + tid;
            const int oc = s >> 3;
            const int og = s & 7;
            const int cg = oc >> 2, o = oc & 3;
            bf16x8 v;
#pragma unroll
            for (int u = 0; u < 8; u++) {
                const int r = og * 8 + u;
                v[u] = (bf16)T[t * 4096 + r * 64 + ((cg ^ (r >> 3)) * 4) + o];
            }
            *(bf16x8*)(dst + (size_t)(c0 + oc) * R + r0 + t * 64 + og * 8) = v;
        }
}

// ---------------------------------------------------------------------------
// GEMM body: C = act(A @ BT^T + bias). A [M][K] bf16, BT [N][K] bf16.
// 128M x 128N tile (m97 geometry: 4 waves, 4x4 frags of 16x16), BK=64,
// DOUBLE-BUFFERED async staging with counted vmcnt: per iter issue 8
// global_load_lds into nxt, s_waitcnt vmcnt(8) (waits only cur's 8), raw
// s_barrier, compute cur (32 MFMA/wave), raw s_barrier. LDS 2x(16+16)KB =
// 64 KB -> 2 blocks/CU. Source-side XOR octet swizzle: slot s ->
// (row=s>>3, oct=(s&7)^(row&7)); fragment ds_read_b128 2-way max (free).
// EXPERT: gz = genre; rows are bucket positions [0,count) at offsets[g].
// [green: R0/R1/R7.  NOTE: BN=64 variant fused with transpose at
//  __launch_bounds__(256,3) fails deterministically (R4/R6) — banned.]
// ---------------------------------------------------------------------------
template <bool EXPERT, bool GATHER_A, bool SCATTER_C, bool GELU, typename CT>
__device__ __forceinline__ void gemm_body(
    int bx, int by, int gz, const bf16* __restrict__ A,
    const bf16* __restrict__ BT, const float* __restrict__ bias,
    CT* __restrict__ Cmat, int N, int K, const int* __restrict__ row_ids,
    const int* __restrict__ offsets, const int* __restrict__ counts,
    bf16* As /*[2][8192]*/, bf16* Bs /*[2][8192]*/) {
    int off = 0, cnt = 1 << 30;
    if (EXPERT) {
        cnt = counts[gz];
        if (by * 128 >= cnt) return;
        off = offsets[gz];
        BT += (size_t)gz * N * K;
        bias += (size_t)gz * N;
    }
    const int m_start = by * 128;
    const int n0 = bx * 128;

    constexpr int BK = 64;  // 8 octets per row
    const int tid = threadIdx.x;
    const int lane = tid & 63;
    const int wave = tid >> 6;
    const int wrow = (wave >> 1) * 64;
    const int wcol = (wave & 1) * 64;
    const int quad = lane >> 4;
    const int l16 = lane & 15;

    // A staging: 1024 slots (128 rows x 8 octets), 4 issues of 256
    const bf16* a_src[4];
#pragma unroll
    for (int i = 0; i < 4; i++) {
        const int s = i * 256 + tid;
        const int row = s >> 3;
        const int col = ((s & 7) ^ (row & 7)) * 8;
        int p = m_start + row;
        size_t arow;
        if (EXPERT) {
            int pp = off + min(p, cnt - 1);
            arow = GATHER_A ? (size_t)row_ids[pp] : (size_t)pp;
        } else {
            arow = (size_t)p;
        }
        a_src[i] = A + arow * (size_t)K + col;
    }
    // B staging: 1024 slots (128 rows x 8 octets), 4 issues
    const bf16* b_src[4];
#pragma unroll
    for (int i = 0; i < 4; i++) {
        const int s = i * 256 + tid;
        const int row = s >> 3;
        const int col = ((s & 7) ^ (row & 7)) * 8;
        b_src[i] = BT + (size_t)(n0 + row) * K + col;
    }
    const int ldsbase = wave * 512;  // wave-uniform (bf16 units); HW adds lane*16B

    floatx4 acc[4][4];
#pragma unroll
    for (int i = 0; i < 4; i++)
#pragma unroll
        for (int j = 0; j < 4; j++)
#pragma unroll
            for (int r = 0; r < 4; r++) acc[i][j][r] = 0.0f;

    const int nK = K / BK;
    // prologue: k=0 into buf0
#pragma unroll
    for (int i = 0; i < 4; i++) async16(&As[i * 2048 + ldsbase], a_src[i]);
#pragma unroll
    for (int i = 0; i < 4; i++) async16(&Bs[i * 2048 + ldsbase], b_src[i]);

    for (int kt = 0; kt < nK; kt++) {
        const int cur = kt & 1, nxt = cur ^ 1;
        const int kn = (kt + 1 < nK) ? (kt + 1) * BK : 0;  // clamp: harmless
#pragma unroll
        for (int i = 0; i < 4; i++)
            async16(&As[nxt * 8192 + i * 2048 + ldsbase], a_src[i] + kn);
#pragma unroll
        for (int i = 0; i < 4; i++)
            async16(&Bs[nxt * 8192 + i * 2048 + ldsbase], b_src[i] + kn);
        WAIT_VM(8);  // cur's 8 loads done; nxt's 8 still in flight
        BARRIER();
#pragma unroll
        for (int ks = 0; ks < 2; ks++) {
            bf16x8 af[4], bfr[4];
            const int cb = ks * 4 + quad;
#pragma unroll
            for (int i = 0; i < 4; i++) {
                const int r = wrow + i * 16 + l16;
                af[i] = *(const bf16x8*)(&As[cur * 8192 + (r * 8 + (cb ^ (r & 7))) * 8]);
            }
#pragma unroll
            for (int j = 0; j < 4; j++) {
                const int n = wcol + j * 16 + l16;
                bfr[j] = *(const bf16x8*)(&Bs[cur * 8192 + (n * 8 + (cb ^ (n & 7))) * 8]);
            }
#pragma unroll
            for (int i = 0; i < 4; i++)
#pragma unroll
                for (int j = 0; j < 4; j++)
                    acc[i][j] = __builtin_amdgcn_mfma_f32_16x16x32_bf16(
                        af[i], bfr[j], acc[i][j], 0, 0, 0);
        }
        BARRIER();  // protect cur before next iter overwrites it
    }

    // epilogue: C/D layout col = lane&15, row = quad*4 + reg  [m89-verified]
#pragma unroll
    for (int j = 0; j < 4; j++) {
        const int n = n0 + wcol + j * 16 + l16;
        const float bv = bias[n];
#pragma unroll
        for (int i = 0; i < 4; i++) {
            const int rbase = wrow + i * 16 + quad * 4;
#pragma unroll
            for (int r = 0; r < 4; r++) {
                const int p = m_start + rbase + r;
                if (EXPERT && p >= cnt) continue;
                float v = acc[i][j][r] + bv;
                if (GELU) v = geluf(v);
                size_t drow;
                if (EXPERT) {
                    const int pp = off + p;
                    drow = SCATTER_C ? (size_t)row_ids[pp] : (size_t)pp;
                } else {
                    drow = (size_t)p;
                }
                Cmat[drow * (size_t)N + n] = (CT)v;
            }
        }
    }
}

// ---------------------------------------------------------------------------
// Dispatch 1: prep (1024 blocks) + Ws1/Ws2 transpose (192) + bucket (1).
// Bucket is block 0 so its serial latency starts first and hides under the
// BW-bound prep/transpose blocks.
// ---------------------------------------------------------------------------
__global__ void setup_kernel(const int* __restrict__ genre,
                             const float* __restrict__ z,
                             const float* __restrict__ mu_t,
                             const float* __restrict__ sg_t,
                             bf16* __restrict__ ng,
                             const float* __restrict__ Ws1,
                             const float* __restrict__ Ws2,
                             bf16* __restrict__ WT1, bf16* __restrict__ WT2,
                             int* __restrict__ counts,
                             int* __restrict__ offsets,
                             int* __restrict__ row_ids) {
    __shared__ float T[2 * 4096];  // 32 KB; bucket aliases first 80 ints
    const int b = blockIdx.x;
    if (b == 0) {
        bucket_body(genre, counts, offsets, row_ids, (int*)T);
    } else if (b < 1025) {
        prep_body(b - 1, genre, z, mu_t, sg_t, ng);
    } else if (b < 1089) {
        transpose_body(Ws1, WT1, 512, b - 1025, T);
    } else {
        transpose_body(Ws2, WT2, 1024, b - 1089, T);
    }
}

// ---------------------------------------------------------------------------
// Dispatches 2/3: shared-MLP GEMM (256 blocks, first in grid) overlapped
// with one expert weight tensor's transpose (1280 blocks). The 60 MB of
// transpose traffic rides in the GEMM dispatch's spare block slots (256
// GEMM blocks on a 512-slot machine) — R9 proved un-fusing this costs
// ~10 µs (transposes serialize in D1 instead of hiding under MFMA).
// ---------------------------------------------------------------------------
__global__ __launch_bounds__(256, 2) void mlp_fused_kernel(
    const bf16* __restrict__ Ain, const bf16* __restrict__ WT,
    const float* __restrict__ bias, bf16* __restrict__ Sout,
    const float* __restrict__ We, bf16* __restrict__ WET, int K) {
    __shared__ bf16 smem[32768];  // 64 KB: As[2][8192] | Bs[2][8192]
    int b = blockIdx.x;
    if (b < 256) {
        gemm_body<false, false, false, true, bf16>(
            b & 7, b >> 3, 0, Ain, WT, bias, Sout, DIM, K, nullptr, nullptr,
            nullptr, smem, smem + 16384);
    } else {
        b -= 256;
        const int e = b >> 7;
        transpose_body(We + (size_t)e * DIM * DIM, WET + (size_t)e * DIM * DIM,
                       1024, b & 127, (float*)smem);
    }
}

// ---------------------------------------------------------------------------
// Dispatches 4/5: expert GEMMs. grid (8, 32, 10); blocks past the bucket
// count return immediately.
// ---------------------------------------------------------------------------
template <bool GATHER_A, bool SCATTER_C, bool GELU, typename CT>
__global__ __launch_bounds__(256, 2) void expert_gemm_kernel(
    const bf16* __restrict__ A, const bf16* __restrict__ BT,
    const float* __restrict__ bias, CT* __restrict__ Cmat,
    const int* __restrict__ row_ids, const int* __restrict__ offsets,
    const int* __restrict__ counts) {
    __shared__ bf16 smem[32768];
    gemm_body<true, GATHER_A, SCATTER_C, GELU, CT>(
        blockIdx.x, blockIdx.y, blockIdx.z, A, BT, bias, Cmat, DIM, DIM,
        row_ids, offsets, counts, smem, smem + 16384);
}

extern "C" void kernel_launch(void* const* d_in, const int* in_sizes, int n_in,
                              void* d_out, int out_size, void* d_ws,
                              size_t ws_size, hipStream_t stream) {
    const int* genre = (const int*)d_in[1];
    const float* z = (const float*)d_in[2];
    const float* mu_t = (const float*)d_in[3];
    const float* sg_t = (const float*)d_in[4];
    const float* Ws1 = (const float*)d_in[5];
    const float* bs1 = (const float*)d_in[6];
    const float* Ws2 = (const float*)d_in[7];
    const float* bs2 = (const float*)d_in[8];
    const float* We1 = (const float*)d_in[9];
    const float* be1 = (const float*)d_in[10];
    const float* We2 = (const float*)d_in[11];
    const float* be2 = (const float*)d_in[12];
    float* out = (float*)d_out;
    char* w = (char*)d_ws;

    // Workspace (~63.1 MB): ints first, weights last.
    int* counts = (int*)w;
    int* offsets = (int*)(w + 256);
    int* row_ids = (int*)(w + 1024);
    char* wb = w + (64 << 10);
    bf16* ng = (bf16*)wb;                          // [4096][512]  4 MB
    bf16* hp = (bf16*)wb;                          // [4096][1024] 8 MB (aliases ng+s1; both dead by expert1)
    bf16* s1 = (bf16*)(wb + ((size_t)4 << 20));    // 8 MB
    bf16* s2 = (bf16*)(wb + ((size_t)12 << 20));   // 8 MB
    bf16* WT1 = (bf16*)(wb + ((size_t)20 << 20));  // [1024][512]  1 MB
    bf16* WT2 = WT1 + (size_t)IN_DIM * DIM;        // [1024][1024] 2 MB
    bf16* WE1T = WT2 + (size_t)DIM * DIM;          // 10x[1024][1024] 20 MB
    bf16* WE2T = WE1T + (size_t)NG * DIM * DIM;    // 20 MB

    // D1: bucket + prep + shared-weight transposes
    setup_kernel<<<1217, 256, 0, stream>>>(genre, z, mu_t, sg_t, ng, Ws1, Ws2,
                                           WT1, WT2, counts, offsets, row_ids);
    // D2: shared MLP layer 1 (K=512)  ||  transpose We1
    mlp_fused_kernel<<<1536, 256, 0, stream>>>(ng, WT1, bs1, s1, We1, WE1T,
                                               IN_DIM);
    // D3: shared MLP layer 2 (K=1024) ||  transpose We2
    mlp_fused_kernel<<<1536, 256, 0, stream>>>(s1, WT2, bs2, s2, We2, WE2T,
                                               DIM);
    // D4: expert layer 1: gather rows by bucket, gelu, write permuted h
    expert_gemm_kernel<true, false, true, bf16>
        <<<dim3(8, 32, 10), 256, 0, stream>>>(s2, WE1T, be1, hp, row_ids,
                                              offsets, counts);
    // D5: expert layer 2: contiguous permuted h, scatter rows to fp32 out
    expert_gemm_kernel<false, true, false, float>
        <<<dim3(8, 32, 10), 256, 0, stream>>>(hp, WE2T, be2, out, row_ids,
                                              offsets, counts);
}